// Round 19
// baseline (241.625 us; speedup 1.0000x reference)
//
#include <hip/hip_runtime.h>

typedef float  f4v   __attribute__((ext_vector_type(4)));
typedef float  f32x4 __attribute__((ext_vector_type(4)));
typedef short  s8v   __attribute__((ext_vector_type(8)));
typedef short  s4v   __attribute__((ext_vector_type(4)));
typedef __bf16 bf16x8 __attribute__((ext_vector_type(8)));

#define N_   197
#define H_   12
#define CIN  3072
#define COUT 1024
#define VSTR 296   // Vt row stride (shorts)
#define ASTR 72    // arena row stride (shorts)
#define BSTR 40    // Bext row stride (shorts)

#define MEMBAR() asm volatile("" ::: "memory")

// Barrier that waits ONLY on LDS ops (lgkmcnt), leaving global loads in flight.
__device__ __forceinline__ void barrier_lds() {
    asm volatile("s_waitcnt lgkmcnt(0)" ::: "memory");
    __builtin_amdgcn_s_barrier();
    asm volatile("" ::: "memory");
}

__device__ __forceinline__ unsigned short f2bf(float f) {
    unsigned u = __float_as_uint(f);
    u += 0x7FFFu + ((u >> 16) & 1u);
    return (unsigned short)(u >> 16);
}
__device__ __forceinline__ f32x4 mfma_bf16(s8v a, s8v b, f32x4 c) {
    return __builtin_amdgcn_mfma_f32_16x16x32_bf16(
        __builtin_bit_cast(bf16x8, a), __builtin_bit_cast(bf16x8, b), c, 0, 0, 0);
}
__device__ __forceinline__ void st4f(volatile unsigned short* p, float a, float b, float c, float d) {
    s4v v;
    v[0] = (short)f2bf(a); v[1] = (short)f2bf(b);
    v[2] = (short)f2bf(c); v[3] = (short)f2bf(d);
    *(volatile s4v*)p = v;
}
__device__ __forceinline__ void st4z(volatile unsigned short* p) {
    s4v v = {0, 0, 0, 0};
    *(volatile s4v*)p = v;
}

// PERSISTENT champion: grid=256, each block serially processes 3 (b,h) pairs
// (pair = i*256 + bid). Identical per-pair structure to the 71.5 us champion
// (fused-bias QK via one-hot Bext MFMA, softmax in regs, arena-window PV),
// but IND/Bext are built ONCE and the 2 extra dispatch cold-starts are gone.
// No cross-pair register state (R9/R13 spill lesson); still 2 barriers/pair
// (B2(i) orders Kl reuse, B1(i+1) orders Vt reuse -- no extra barrier needed).
__launch_bounds__(1024, 4)
__global__ void attn_super(const float* __restrict__ x,
                           const float* __restrict__ tkv,
                           const float* __restrict__ tkh,
                           const float* __restrict__ tvv,
                           const float* __restrict__ tvh,
                           float* __restrict__ out) {
    __shared__ __align__(16) unsigned short Kl[272 * 72];
    __shared__ __align__(16) unsigned short Vt[64 * VSTR];
    __shared__ __align__(16) unsigned short AR[16][16 * ASTR];
    __shared__ __align__(16) unsigned short INDv[16 * 224];
    __shared__ __align__(16) unsigned short INDh[16 * 224];
    __shared__ __align__(16) unsigned short Bext[224 * BSTR];

    const int bid = blockIdx.x;    // 0..255
    const int tid = threadIdx.x;
    const int w  = tid >> 6;       // wave 0..15
    const int l  = tid & 63;
    const int lg = l >> 4;         // 16-lane group
    const int ln = l & 15;

    // ---- build indicator tables ONCE (VALU-only) ----
    for (int idx = tid; idx < 16 * 224; idx += 1024) {
        int m = idx / 224, k = idx % 224;
        int km1 = k - 1;
        bool kv = (k >= 1 && k <= 196);
        INDv[idx] = (kv && (km1 / 14) == m) ? (unsigned short)0x3F80 : (unsigned short)0;
        INDh[idx] = (kv && (km1 % 14) == m) ? (unsigned short)0x3F80 : (unsigned short)0;
    }
    for (int idx = tid; idx < 224 * 32; idx += 1024) {
        int k = idx >> 5, c = idx & 31;
        unsigned short v = 0;
        if (k >= 1 && k <= 196) {
            int mj = (k - 1) / 14, cj = (k - 1) - mj * 14;
            if (c == mj || c == 16 + cj) v = (unsigned short)0x3F80;
        } else if (k == 0) {
            if (c == 15 || c == 31) v = (unsigned short)0x3F80;
        }
        Bext[k * BSTR + c] = v;
    }

    const int tile = w, qb = tile * 16;
    const unsigned short* ar = &AR[w][0];
    volatile unsigned short* arv = &AR[w][0];

    for (int ip = 0; ip < 3; ++ip) {
        const int pair = ip * 256 + bid;
        const int b = pair / H_, h = pair - b * H_;
        const float* xb = x + (size_t)b * N_ * CIN;

        // ---- zero-pad output channels [768,1024) (h<4 pairs) ----
        if (h < 4) {
            float* oz = out + (size_t)b * N_ * COUT + 768 + h * 64;
            for (int idx = tid; idx < N_ * 16; idx += 1024) {
                int row = idx >> 4, c4 = idx & 15;
                f4v z = {0.f, 0.f, 0.f, 0.f};
                *(f4v*)(oz + (size_t)row * COUT + c4 * 4) = z;
            }
        }

        // ---- PROLOGUE: issue ALL global loads (K, then Q, then V) ----
        f4v kr[5];
        #pragma unroll
        for (int it = 0; it < 5; ++it) {
            int idx = it * 1024 + tid;
            bool a5 = (it < 4) || (tid < 256);       // 272*16 = 4352
            int row = idx >> 4, d0 = (idx & 15) * 4;
            f4v v = {0.f, 0.f, 0.f, 0.f};
            if (a5) {
                if (row < N_)                     v = *(const f4v*)(xb + (size_t)row * CIN + 768 + h * 64 + d0);
                else if (row >= 208 && row < 238) v = *(const f4v*)(tkv + (row - 208) * 64 + d0);
                else if (row >= 240 && row < 270) v = *(const f4v*)(tkh + (row - 240) * 64 + d0);
            }
            kr[it] = v;
        }
        f4v q1[2], q2[2];
        if (w < 13) {
            int qrow = qb + ln; if (qrow > 196) qrow = 196;
            const float* qp = xb + (size_t)qrow * CIN + h * 64;
            #pragma unroll
            for (int s2 = 0; s2 < 2; ++s2) {
                q1[s2] = *(const f4v*)(qp + s2 * 32 + lg * 8);
                q2[s2] = *(const f4v*)(qp + s2 * 32 + lg * 8 + 4);
            }
        }
        f4v vr[5];
        #pragma unroll
        for (int it = 0; it < 5; ++it) {
            int idx = it * 1024 + tid;
            bool a5 = (it < 4) || (tid < 512);       // 288*16 = 4608
            int j = idx % 288, d0 = (idx / 288) * 4;
            f4v v = {0.f, 0.f, 0.f, 0.f};
            if (a5) {
                if (j < N_)                     v = *(const f4v*)(xb + (size_t)j * CIN + 1536 + h * 64 + d0);
                else if (j >= 224 && j < 254)   v = *(const f4v*)(tvv + (j - 224) * 64 + d0);
                else if (j >= 256 && j < 286)   v = *(const f4v*)(tvh + (j - 256) * 64 + d0);
            }
            vr[it] = v;
        }

        // ---- write K -> LDS (forces wait on K loads only; V stays in flight) ----
        #pragma unroll
        for (int it = 0; it < 5; ++it) {
            int idx = it * 1024 + tid;
            bool a5 = (it < 4) || (tid < 256);
            if (a5) {
                int row = idx >> 4, d0 = (idx & 15) * 4;
                f4v v = kr[it];
                s4v pk;
                pk[0] = (short)f2bf(v[0]); pk[1] = (short)f2bf(v[1]);
                pk[2] = (short)f2bf(v[2]); pk[3] = (short)f2bf(v[3]);
                *(s4v*)(&Kl[row * 72 + d0]) = pk;
            }
        }
        barrier_lds();   // B1: Kl (+ tables on ip==0) ready; orders Vt(i) writes after PV(i-1)

        f32x4 S[13];
        float rsq[4], p0q[4];
        int ritq[4], citq[4];
        if (w < 13) {
            // per-lane shift constants for q-row i = qb + ln
            const int iL  = qb + ln;
            const int im1 = (iL > 0) ? iL - 1 : 0;
            const int rit = im1 / 14;
            const int cit = im1 - rit * 14;

            // Q frags from prefetched regs (pre-scaled 1/8)
            s8v aq[2];
            #pragma unroll
            for (int s2 = 0; s2 < 2; ++s2) {
                #pragma unroll
                for (int e = 0; e < 4; ++e) {
                    aq[s2][e]     = (short)f2bf(q1[s2][e] * 0.125f);
                    aq[s2][e + 4] = (short)f2bf(q2[s2][e] * 0.125f);
                }
            }
            // ---- table tiles -> pre-shifted qt2 (arena cols 0..31, row = q = ln) ----
            float spv = 0.f, sph = 0.f;
            #pragma unroll
            for (int tt = 0; tt < 4; ++tt) {
                f32x4 acc = {0.f, 0.f, 0.f, 0.f};
                #pragma unroll
                for (int s2 = 0; s2 < 2; ++s2) {
                    const s8v bk = *(const s8v*)(&Kl[((13 + tt) * 16 + ln) * 72 + s2 * 32 + lg * 8]);
                    acc = mfma_bf16(bk, aq[s2], acc);
                }
                const bool isV  = (tt < 2);
                const int mbase = (tt & 1) * 16;
                const int shift = isV ? rit : cit;
                const int cbase = isV ? 0 : 16;
                const bool skip0 = (tile == 0 && ln == 0);   // row q==0 handled specially
                #pragma unroll
                for (int r = 0; r < 4; ++r) {
                    int m = mbase + 4 * lg + r;
                    int t = m + shift - 15;
                    if (!skip0 && m < 30 && t >= 0 && t < 15)
                        arv[ln * ASTR + cbase + t] = f2bf(acc[r]);
                    if (!skip0 && m == 0)
                        arv[ln * ASTR + cbase + 15] = f2bf(acc[r]);   // k==0 slot
                }
                if (tile == 0 && l == 0) {
                    if (tt == 0) spv = acc[0];
                    if (tt == 2) sph = acc[0];
                }
            }
            // row q==0 (i==0): bias is qtv[0][0]+qth[0][0] for ALL k -> constant rows
            if (tile == 0 && l == 0) {
                unsigned short v0 = f2bf(spv), h0 = f2bf(sph);
                #pragma unroll
                for (int t = 0; t < 16; ++t) {
                    arv[t] = v0;
                    arv[16 + t] = h0;
                }
            }
            MEMBAR();   // qt2 scatter writes -> aq2 vector read
            const s8v aq2 = *(const s8v*)(&ar[ln * ASTR + lg * 8]);
            // ---- swapped QK^T with fused bias: S = Bext.qt2 + K.Q ----
            #pragma unroll
            for (int ct = 0; ct < 13; ++ct) {
                const s8v be = *(const s8v*)(&Bext[(ct * 16 + ln) * BSTR + lg * 8]);
                f32x4 acc = {0.f, 0.f, 0.f, 0.f};
                acc = mfma_bf16(be, aq2, acc);
                #pragma unroll
                for (int s2 = 0; s2 < 2; ++s2) {
                    const s8v bk = *(const s8v*)(&Kl[(ct * 16 + ln) * 72 + s2 * 32 + lg * 8]);
                    acc = mfma_bf16(bk, aq[s2], acc);
                }
                S[ct] = acc;
            }
        }
        // ---- write V -> LDS (V loads landed under table+QK compute) ----
        #pragma unroll
        for (int it = 0; it < 5; ++it) {
            int idx = it * 1024 + tid;
            bool a5 = (it < 4) || (tid < 512);
            if (a5) {
                int j = idx % 288, d0 = (idx / 288) * 4;
                f4v v = vr[it];
                #pragma unroll
                for (int e = 0; e < 4; ++e)
                    Vt[(d0 + e) * VSTR + j] = f2bf(v[e]);
            }
        }

        if (w < 13) {
            // ---- softmax: pure exp + row-sum (bias already in S) ----
            float rs4[4] = {0.f, 0.f, 0.f, 0.f};
            #pragma unroll
            for (int ct = 0; ct < 13; ++ct) {
                #pragma unroll
                for (int r = 0; r < 4; ++r) {
                    float p = __expf(S[ct][r]);
                    if (ct == 12) { if (4 * lg + r > 4) p = 0.f; }   // k>196 invalid
                    S[ct][r] = p;
                    rs4[r] += p;
                }
            }
            float rs = (rs4[0] + rs4[1]) + (rs4[2] + rs4[3]);
            rs += __shfl_xor(rs, 16);
            rs += __shfl_xor(rs, 32);
            float p00 = S[0][0];
            #pragma unroll
            for (int r = 0; r < 4; ++r) {
                rsq[r] = __shfl(rs,  4 * lg + r);
                p0q[r] = __shfl(p00, 4 * lg + r);
            }
            #pragma unroll
            for (int r = 0; r < 4; ++r) {
                int qr2 = qb + 4 * lg + r;
                int im  = (qr2 > 0) ? qr2 - 1 : 0;
                ritq[r] = im / 14;
                citq[r] = im - ritq[r] * 14;
            }
        }
        barrier_lds();   // B2: Vt ready; Kl free for next pair

        if (w < 13) {
            // ---- PV + bins via sliding 64-col arena window ----
            f32x4 oacc[4];
            #pragma unroll
            for (int nt = 0; nt < 4; ++nt) { f32x4 z = {0.f,0.f,0.f,0.f}; oacc[nt] = z; }
            f32x4 cwv = {0.f,0.f,0.f,0.f}, cwh = {0.f,0.f,0.f,0.f};

            #pragma unroll
            for (int win = 0; win < 3; ++win) {         // k 0..63, 64..127, 128..191
                MEMBAR();
                #pragma unroll
                for (int cc = 0; cc < 4; ++cc) {
                    int ct = win * 4 + cc;
                    st4f(&arv[ln * ASTR + cc * 16 + 4 * lg], S[ct][0], S[ct][1], S[ct][2], S[ct][3]);
                }
                MEMBAR();
                #pragma unroll
                for (int kk = 0; kk < 2; ++kk) {
                    int kt = win * 2 + kk;
                    const s8v ap = *(const s8v*)(&ar[ln * ASTR + kk * 32 + lg * 8]);
                    #pragma unroll
                    for (int nt = 0; nt < 4; ++nt) {
                        const s8v bv = *(const s8v*)(&Vt[(nt * 16 + ln) * VSTR + kt * 32 + lg * 8]);
                        oacc[nt] = mfma_bf16(ap, bv, oacc[nt]);
                    }
                    const s8v bi = *(const s8v*)(&INDv[ln * 224 + kt * 32 + lg * 8]);
                    cwv = mfma_bf16(ap, bi, cwv);
                    const s8v bh = *(const s8v*)(&INDh[ln * 224 + kt * 32 + lg * 8]);
                    cwh = mfma_bf16(ap, bh, cwh);
                }
            }
            { // window 3: k 192..255  (P ct12 | zeros | wv bins)
                MEMBAR();
                st4f(&arv[ln * ASTR + 4 * lg], S[12][0], S[12][1], S[12][2], S[12][3]);
                st4z(&arv[ln * ASTR + 16 + 4 * lg]);
                st4z(&arv[ln * ASTR + 32 + lg * 8]);
                st4z(&arv[ln * ASTR + 36 + lg * 8]);
                MEMBAR();
                { // kt6 (k 192..223)
                    const s8v ap = *(const s8v*)(&ar[ln * ASTR + lg * 8]);
                    #pragma unroll
                    for (int nt = 0; nt < 4; ++nt) {
                        const s8v bv = *(const s8v*)(&Vt[(nt * 16 + ln) * VSTR + 192 + lg * 8]);
                        oacc[nt] = mfma_bf16(ap, bv, oacc[nt]);
                    }
                    const s8v bi = *(const s8v*)(&INDv[ln * 224 + 192 + lg * 8]);
                    cwv = mfma_bf16(ap, bi, cwv);
                    const s8v bh = *(const s8v*)(&INDh[ln * 224 + 192 + lg * 8]);
                    cwh = mfma_bf16(ap, bh, cwh);
                }
                MEMBAR();
                // scatter wv bins: C_wv[q=4lg+r][m=ln] -> col 32 + (ln - ritq + 15)
                #pragma unroll
                for (int r = 0; r < 4; ++r) {
                    int q = 4 * lg + r;
                    bool isRow0 = (tile == 0) && (q == 0);
                    if (ln <= 13 && !isRow0)
                        arv[q * ASTR + 47 + ln - ritq[r]] = f2bf(cwv[r]);
                    if (ln == 15)
                        arv[q * ASTR + 32] = f2bf(isRow0 ? rsq[r] : p0q[r]);
                }
                MEMBAR();
                { // kt7 (k 224..255 = tv_v bins)
                    const s8v ap = *(const s8v*)(&ar[ln * ASTR + 32 + lg * 8]);
                    #pragma unroll
                    for (int nt = 0; nt < 4; ++nt) {
                        const s8v bv = *(const s8v*)(&Vt[(nt * 16 + ln) * VSTR + 224 + lg * 8]);
                        oacc[nt] = mfma_bf16(ap, bv, oacc[nt]);
                    }
                }
            }
            { // window 4: k 256..287 (wh bins)
                MEMBAR();
                st4z(&arv[ln * ASTR + lg * 8]);
                st4z(&arv[ln * ASTR + 4 + lg * 8]);
                MEMBAR();
                #pragma unroll
                for (int r = 0; r < 4; ++r) {
                    int q = 4 * lg + r;
                    bool isRow0 = (tile == 0) && (q == 0);
                    if (ln <= 13 && !isRow0)
                        arv[q * ASTR + 15 + ln - citq[r]] = f2bf(cwh[r]);
                    if (ln == 15)
                        arv[q * ASTR + 0] = f2bf(isRow0 ? rsq[r] : p0q[r]);
                }
                MEMBAR();
                { // kt8
                    const s8v ap = *(const s8v*)(&ar[ln * ASTR + lg * 8]);
                    #pragma unroll
                    for (int nt = 0; nt < 4; ++nt) {
                        const s8v bv = *(const s8v*)(&Vt[(nt * 16 + ln) * VSTR + 256 + lg * 8]);
                        oacc[nt] = mfma_bf16(ap, bv, oacc[nt]);
                    }
                }
            }
            // ---- normalize + store (C row = q = 4lg+r, col = d = nt*16+ln) ----
            #pragma unroll
            for (int r = 0; r < 4; ++r) {
                int n = qb + 4 * lg + r;
                if (n < N_) {
                    float sc = 1.0f / rsq[r];
                    float* orow = out + ((size_t)b * N_ + n) * COUT + h * 64;
                    #pragma unroll
                    for (int nt = 0; nt < 4; ++nt)
                        orow[nt * 16 + ln] = oacc[nt][r] * sc;
                }
            }
        }
        // No extra barrier: Kl(i+1) writes are ordered after QK(i) by B2(i);
        // Vt(i+1) writes are ordered after PV(i) by B1(i+1).
    }
}

extern "C" void kernel_launch(void* const* d_in, const int* in_sizes, int n_in,
                              void* d_out, int out_size, void* d_ws, size_t ws_size,
                              hipStream_t stream) {
    const float* x   = (const float*)d_in[0];
    const float* tkv = (const float*)d_in[1];
    const float* tkh = (const float*)d_in[2];
    const float* tvv = (const float*)d_in[3];
    const float* tvh = (const float*)d_in[4];
    float* o = (float*)d_out;
    attn_super<<<dim3(256), dim3(1024), 0, stream>>>(x, tkv, tkh, tvv, tvh, o);
}

// Round 20
// 71.457 us; speedup vs baseline: 3.3814x; 3.3814x over previous
//
#include <hip/hip_runtime.h>

typedef float  f4v   __attribute__((ext_vector_type(4)));
typedef float  f32x4 __attribute__((ext_vector_type(4)));
typedef short  s8v   __attribute__((ext_vector_type(8)));
typedef short  s4v   __attribute__((ext_vector_type(4)));
typedef __bf16 bf16x8 __attribute__((ext_vector_type(8)));

#define N_   197
#define H_   12
#define CIN  3072
#define COUT 1024
#define VSTR 296   // Vt row stride (shorts)
#define ASTR 72    // arena row stride (shorts)
#define BSTR 40    // Bext row stride (shorts)

#define MEMBAR() asm volatile("" ::: "memory")

// Barrier that waits ONLY on LDS ops (lgkmcnt), leaving global loads in
// flight. __syncthreads() would emit s_waitcnt vmcnt(0) and drain the V
// prefetch.
__device__ __forceinline__ void barrier_lds() {
    asm volatile("s_waitcnt lgkmcnt(0)" ::: "memory");
    __builtin_amdgcn_s_barrier();
    asm volatile("" ::: "memory");
}

__device__ __forceinline__ unsigned short f2bf(float f) {
    unsigned u = __float_as_uint(f);
    u += 0x7FFFu + ((u >> 16) & 1u);
    return (unsigned short)(u >> 16);
}
__device__ __forceinline__ f32x4 mfma_bf16(s8v a, s8v b, f32x4 c) {
    return __builtin_amdgcn_mfma_f32_16x16x32_bf16(
        __builtin_bit_cast(bf16x8, a), __builtin_bit_cast(bf16x8, b), c, 0, 0, 0);
}
__device__ __forceinline__ void st4f(volatile unsigned short* p, float a, float b, float c, float d) {
    s4v v;
    v[0] = (short)f2bf(a); v[1] = (short)f2bf(b);
    v[2] = (short)f2bf(c); v[3] = (short)f2bf(d);
    *(volatile s4v*)p = v;
}
__device__ __forceinline__ void st4z(volatile unsigned short* p) {
    s4v v = {0, 0, 0, 0};
    *(volatile s4v*)p = v;
}

// One block per (b,h), 1024 threads = 16 waves. Wave w (<13) owns q-tile w.
// Swapped QK^T with FUSED rel-pos bias (one-hot Bext MFMA), softmax = pure
// exp+sum in registers, PV + bins via sliding 64-col arena windows.
// Barriers are LDS-only (raw s_barrier) so the V prefetch genuinely stays
// in flight across B1 and lands under the QK phase.
__launch_bounds__(1024, 1)
__global__ void attn_super(const float* __restrict__ x,
                           const float* __restrict__ tkv,
                           const float* __restrict__ tkh,
                           const float* __restrict__ tvv,
                           const float* __restrict__ tvh,
                           float* __restrict__ out) {
    __shared__ __align__(16) unsigned short Kl[272 * 72];
    __shared__ __align__(16) unsigned short Vt[64 * VSTR];
    __shared__ __align__(16) unsigned short AR[16][16 * ASTR];
    __shared__ __align__(16) unsigned short INDv[16 * 224];
    __shared__ __align__(16) unsigned short INDh[16 * 224];
    __shared__ __align__(16) unsigned short Bext[224 * BSTR];

    const int bid = blockIdx.x;
    const int b = bid / H_, h = bid % H_;
    const int tid = threadIdx.x;
    const int w  = tid >> 6;       // wave 0..15
    const int l  = tid & 63;
    const int lg = l >> 4;         // 16-lane group
    const int ln = l & 15;

    const float* xb = x + (size_t)b * N_ * CIN;

    // ---- zero-pad output channels [768,1024) (h<4 blocks): issue early ----
    if (h < 4) {
        float* oz = out + (size_t)b * N_ * COUT + 768 + h * 64;
        for (int idx = tid; idx < N_ * 16; idx += 1024) {
            int row = idx >> 4, c4 = idx & 15;
            f4v z = {0.f, 0.f, 0.f, 0.f};
            *(f4v*)(oz + (size_t)row * COUT + c4 * 4) = z;
        }
    }

    // ---- PROLOGUE: issue ALL global loads (K, then Q, then V) ----
    f4v kr[5];
    #pragma unroll
    for (int it = 0; it < 5; ++it) {
        int idx = it * 1024 + tid;
        bool a5 = (it < 4) || (tid < 256);       // 272*16 = 4352
        int row = idx >> 4, d0 = (idx & 15) * 4;
        f4v v = {0.f, 0.f, 0.f, 0.f};
        if (a5) {
            if (row < N_)                     v = *(const f4v*)(xb + (size_t)row * CIN + 768 + h * 64 + d0);
            else if (row >= 208 && row < 238) v = *(const f4v*)(tkv + (row - 208) * 64 + d0);
            else if (row >= 240 && row < 270) v = *(const f4v*)(tkh + (row - 240) * 64 + d0);
        }
        kr[it] = v;
    }
    f4v q1[2], q2[2];
    if (w < 13) {
        int qrow = w * 16 + ln; if (qrow > 196) qrow = 196;
        const float* qp = xb + (size_t)qrow * CIN + h * 64;
        #pragma unroll
        for (int s2 = 0; s2 < 2; ++s2) {
            q1[s2] = *(const f4v*)(qp + s2 * 32 + lg * 8);
            q2[s2] = *(const f4v*)(qp + s2 * 32 + lg * 8 + 4);
        }
    }
    f4v vr[5];
    #pragma unroll
    for (int it = 0; it < 5; ++it) {
        int idx = it * 1024 + tid;
        bool a5 = (it < 4) || (tid < 512);       // 288*16 = 4608
        int j = idx % 288, d0 = (idx / 288) * 4;
        f4v v = {0.f, 0.f, 0.f, 0.f};
        if (a5) {
            if (j < N_)                     v = *(const f4v*)(xb + (size_t)j * CIN + 1536 + h * 64 + d0);
            else if (j >= 224 && j < 254)   v = *(const f4v*)(tvv + (j - 224) * 64 + d0);
            else if (j >= 256 && j < 286)   v = *(const f4v*)(tvh + (j - 256) * 64 + d0);
        }
        vr[it] = v;
    }

    // ---- write K -> LDS (forces wait on K loads only; V stays in flight) ----
    #pragma unroll
    for (int it = 0; it < 5; ++it) {
        int idx = it * 1024 + tid;
        bool a5 = (it < 4) || (tid < 256);
        if (a5) {
            int row = idx >> 4, d0 = (idx & 15) * 4;
            f4v v = kr[it];
            s4v pk;
            pk[0] = (short)f2bf(v[0]); pk[1] = (short)f2bf(v[1]);
            pk[2] = (short)f2bf(v[2]); pk[3] = (short)f2bf(v[3]);
            *(s4v*)(&Kl[row * 72 + d0]) = pk;
        }
    }
    // ---- build indicator tables (VALU-only) ----
    for (int idx = tid; idx < 16 * 224; idx += 1024) {
        int m = idx / 224, k = idx % 224;
        int km1 = k - 1;
        bool kv = (k >= 1 && k <= 196);
        INDv[idx] = (kv && (km1 / 14) == m) ? (unsigned short)0x3F80 : (unsigned short)0;
        INDh[idx] = (kv && (km1 % 14) == m) ? (unsigned short)0x3F80 : (unsigned short)0;
    }
    // ---- build Bext one-hot bias matrix [224][BSTR], cols 0..31 used ----
    for (int idx = tid; idx < 224 * 32; idx += 1024) {
        int k = idx >> 5, c = idx & 31;
        unsigned short v = 0;
        if (k >= 1 && k <= 196) {
            int mj = (k - 1) / 14, cj = (k - 1) - mj * 14;
            if (c == mj || c == 16 + cj) v = (unsigned short)0x3F80;
        } else if (k == 0) {
            if (c == 15 || c == 31) v = (unsigned short)0x3F80;
        }
        Bext[k * BSTR + c] = v;
    }
    barrier_lds();   // B1: Kl + IND + Bext ready (V loads still in flight)

    const int tile = w, qb = tile * 16;
    const unsigned short* ar = &AR[w][0];
    volatile unsigned short* arv = &AR[w][0];

    f32x4 S[13];
    float rsq[4], p0q[4];
    int ritq[4], citq[4];
    if (w < 13) {
        // per-lane shift constants for q-row i = qb + ln
        const int iL  = qb + ln;
        const int im1 = (iL > 0) ? iL - 1 : 0;
        const int rit = im1 / 14;
        const int cit = im1 - rit * 14;

        // Q frags from prefetched regs (pre-scaled 1/8)
        s8v aq[2];
        #pragma unroll
        for (int s2 = 0; s2 < 2; ++s2) {
            #pragma unroll
            for (int e = 0; e < 4; ++e) {
                aq[s2][e]     = (short)f2bf(q1[s2][e] * 0.125f);
                aq[s2][e + 4] = (short)f2bf(q2[s2][e] * 0.125f);
            }
        }
        // ---- table tiles -> pre-shifted qt2 (arena cols 0..31, row = q = ln) ----
        float spv = 0.f, sph = 0.f;
        #pragma unroll
        for (int tt = 0; tt < 4; ++tt) {
            f32x4 acc = {0.f, 0.f, 0.f, 0.f};
            #pragma unroll
            for (int s2 = 0; s2 < 2; ++s2) {
                const s8v bk = *(const s8v*)(&Kl[((13 + tt) * 16 + ln) * 72 + s2 * 32 + lg * 8]);
                acc = mfma_bf16(bk, aq[s2], acc);
            }
            const bool isV  = (tt < 2);
            const int mbase = (tt & 1) * 16;
            const int shift = isV ? rit : cit;
            const int cbase = isV ? 0 : 16;
            const bool skip0 = (tile == 0 && ln == 0);   // row q==0 handled specially
            #pragma unroll
            for (int r = 0; r < 4; ++r) {
                int m = mbase + 4 * lg + r;
                int t = m + shift - 15;
                if (!skip0 && m < 30 && t >= 0 && t < 15)
                    arv[ln * ASTR + cbase + t] = f2bf(acc[r]);
                if (!skip0 && m == 0)
                    arv[ln * ASTR + cbase + 15] = f2bf(acc[r]);   // k==0 slot
            }
            if (tile == 0 && l == 0) {
                if (tt == 0) spv = acc[0];
                if (tt == 2) sph = acc[0];
            }
        }
        // row q==0 (i==0): bias is qtv[0][0]+qth[0][0] for ALL k -> constant rows
        if (tile == 0 && l == 0) {
            unsigned short v0 = f2bf(spv), h0 = f2bf(sph);
            #pragma unroll
            for (int t = 0; t < 16; ++t) {
                arv[t] = v0;
                arv[16 + t] = h0;
            }
        }
        MEMBAR();   // qt2 scatter writes -> aq2 vector read
        const s8v aq2 = *(const s8v*)(&ar[ln * ASTR + lg * 8]);
        // ---- swapped QK^T with fused bias: S = Bext.qt2 + K.Q ----
        #pragma unroll
        for (int ct = 0; ct < 13; ++ct) {
            const s8v be = *(const s8v*)(&Bext[(ct * 16 + ln) * BSTR + lg * 8]);
            f32x4 acc = {0.f, 0.f, 0.f, 0.f};
            acc = mfma_bf16(be, aq2, acc);
            #pragma unroll
            for (int s2 = 0; s2 < 2; ++s2) {
                const s8v bk = *(const s8v*)(&Kl[(ct * 16 + ln) * 72 + s2 * 32 + lg * 8]);
                acc = mfma_bf16(bk, aq[s2], acc);
            }
            S[ct] = acc;
        }
    }
    // ---- write V -> LDS (V loads landed under table+QK compute) ----
    #pragma unroll
    for (int it = 0; it < 5; ++it) {
        int idx = it * 1024 + tid;
        bool a5 = (it < 4) || (tid < 512);
        if (a5) {
            int j = idx % 288, d0 = (idx / 288) * 4;
            f4v v = vr[it];
            #pragma unroll
            for (int e = 0; e < 4; ++e)
                Vt[(d0 + e) * VSTR + j] = f2bf(v[e]);
        }
    }

    if (w < 13) {
        // ---- softmax: pure exp + row-sum (bias already in S) ----
        float rs4[4] = {0.f, 0.f, 0.f, 0.f};
        #pragma unroll
        for (int ct = 0; ct < 13; ++ct) {
            #pragma unroll
            for (int r = 0; r < 4; ++r) {
                float p = __expf(S[ct][r]);
                if (ct == 12) { if (4 * lg + r > 4) p = 0.f; }   // k>196 invalid
                S[ct][r] = p;
                rs4[r] += p;
            }
        }
        float rs = (rs4[0] + rs4[1]) + (rs4[2] + rs4[3]);
        rs += __shfl_xor(rs, 16);
        rs += __shfl_xor(rs, 32);
        float p00 = S[0][0];
        #pragma unroll
        for (int r = 0; r < 4; ++r) {
            rsq[r] = __shfl(rs,  4 * lg + r);
            p0q[r] = __shfl(p00, 4 * lg + r);
        }
        #pragma unroll
        for (int r = 0; r < 4; ++r) {
            int qr2 = qb + 4 * lg + r;
            int im  = (qr2 > 0) ? qr2 - 1 : 0;
            ritq[r] = im / 14;
            citq[r] = im - ritq[r] * 14;
        }
    }
    barrier_lds();   // B2: Vt ready (no outstanding global loads needed past here)

    if (w >= 13) return;

    // ---- PV + bins via sliding 64-col arena window ----
    f32x4 oacc[4];
    #pragma unroll
    for (int nt = 0; nt < 4; ++nt) { f32x4 z = {0.f,0.f,0.f,0.f}; oacc[nt] = z; }
    f32x4 cwv = {0.f,0.f,0.f,0.f}, cwh = {0.f,0.f,0.f,0.f};

    #pragma unroll
    for (int win = 0; win < 3; ++win) {         // k 0..63, 64..127, 128..191
        MEMBAR();
        #pragma unroll
        for (int cc = 0; cc < 4; ++cc) {
            int ct = win * 4 + cc;
            st4f(&arv[ln * ASTR + cc * 16 + 4 * lg], S[ct][0], S[ct][1], S[ct][2], S[ct][3]);
        }
        MEMBAR();
        #pragma unroll
        for (int kk = 0; kk < 2; ++kk) {
            int kt = win * 2 + kk;
            const s8v ap = *(const s8v*)(&ar[ln * ASTR + kk * 32 + lg * 8]);
            #pragma unroll
            for (int nt = 0; nt < 4; ++nt) {
                const s8v bv = *(const s8v*)(&Vt[(nt * 16 + ln) * VSTR + kt * 32 + lg * 8]);
                oacc[nt] = mfma_bf16(ap, bv, oacc[nt]);
            }
            const s8v bi = *(const s8v*)(&INDv[ln * 224 + kt * 32 + lg * 8]);
            cwv = mfma_bf16(ap, bi, cwv);
            const s8v bh = *(const s8v*)(&INDh[ln * 224 + kt * 32 + lg * 8]);
            cwh = mfma_bf16(ap, bh, cwh);
        }
    }
    { // window 3: k 192..255  (P ct12 | zeros | wv bins)
        MEMBAR();
        st4f(&arv[ln * ASTR + 4 * lg], S[12][0], S[12][1], S[12][2], S[12][3]);
        st4z(&arv[ln * ASTR + 16 + 4 * lg]);
        st4z(&arv[ln * ASTR + 32 + lg * 8]);
        st4z(&arv[ln * ASTR + 36 + lg * 8]);
        MEMBAR();
        { // kt6 (k 192..223)
            const s8v ap = *(const s8v*)(&ar[ln * ASTR + lg * 8]);
            #pragma unroll
            for (int nt = 0; nt < 4; ++nt) {
                const s8v bv = *(const s8v*)(&Vt[(nt * 16 + ln) * VSTR + 192 + lg * 8]);
                oacc[nt] = mfma_bf16(ap, bv, oacc[nt]);
            }
            const s8v bi = *(const s8v*)(&INDv[ln * 224 + 192 + lg * 8]);
            cwv = mfma_bf16(ap, bi, cwv);
            const s8v bh = *(const s8v*)(&INDh[ln * 224 + 192 + lg * 8]);
            cwh = mfma_bf16(ap, bh, cwh);
        }
        MEMBAR();
        // scatter wv bins: C_wv[q=4lg+r][m=ln] -> col 32 + (ln - ritq + 15)
        #pragma unroll
        for (int r = 0; r < 4; ++r) {
            int q = 4 * lg + r;
            bool isRow0 = (tile == 0) && (q == 0);
            if (ln <= 13 && !isRow0)
                arv[q * ASTR + 47 + ln - ritq[r]] = f2bf(cwv[r]);
            if (ln == 15)
                arv[q * ASTR + 32] = f2bf(isRow0 ? rsq[r] : p0q[r]);
        }
        MEMBAR();
        { // kt7 (k 224..255 = tv_v bins)
            const s8v ap = *(const s8v*)(&ar[ln * ASTR + 32 + lg * 8]);
            #pragma unroll
            for (int nt = 0; nt < 4; ++nt) {
                const s8v bv = *(const s8v*)(&Vt[(nt * 16 + ln) * VSTR + 224 + lg * 8]);
                oacc[nt] = mfma_bf16(ap, bv, oacc[nt]);
            }
        }
    }
    { // window 4: k 256..287 (wh bins)
        MEMBAR();
        st4z(&arv[ln * ASTR + lg * 8]);
        st4z(&arv[ln * ASTR + 4 + lg * 8]);
        MEMBAR();
        #pragma unroll
        for (int r = 0; r < 4; ++r) {
            int q = 4 * lg + r;
            bool isRow0 = (tile == 0) && (q == 0);
            if (ln <= 13 && !isRow0)
                arv[q * ASTR + 15 + ln - citq[r]] = f2bf(cwh[r]);
            if (ln == 15)
                arv[q * ASTR + 0] = f2bf(isRow0 ? rsq[r] : p0q[r]);
        }
        MEMBAR();
        { // kt8
            const s8v ap = *(const s8v*)(&ar[ln * ASTR + lg * 8]);
            #pragma unroll
            for (int nt = 0; nt < 4; ++nt) {
                const s8v bv = *(const s8v*)(&Vt[(nt * 16 + ln) * VSTR + 256 + lg * 8]);
                oacc[nt] = mfma_bf16(ap, bv, oacc[nt]);
            }
        }
    }
    // ---- normalize + store (C row = q = 4lg+r, col = d = nt*16+ln) ----
    #pragma unroll
    for (int r = 0; r < 4; ++r) {
        int n = qb + 4 * lg + r;
        if (n < N_) {
            float sc = 1.0f / rsq[r];
            float* orow = out + ((size_t)b * N_ + n) * COUT + h * 64;
            #pragma unroll
            for (int nt = 0; nt < 4; ++nt)
                orow[nt * 16 + ln] = oacc[nt][r] * sc;
        }
    }
}

extern "C" void kernel_launch(void* const* d_in, const int* in_sizes, int n_in,
                              void* d_out, int out_size, void* d_ws, size_t ws_size,
                              hipStream_t stream) {
    const float* x   = (const float*)d_in[0];
    const float* tkv = (const float*)d_in[1];
    const float* tkh = (const float*)d_in[2];
    const float* tvv = (const float*)d_in[3];
    const float* tvh = (const float*)d_in[4];
    float* o = (float*)d_out;
    attn_super<<<dim3(64 * H_), dim3(1024), 0, stream>>>(x, tkv, tkh, tvv, tvh, o);
}